// Round 3
// baseline (187.641 us; speedup 1.0000x reference)
//
#include <hip/hip_runtime.h>
#include <hip/hip_bf16.h>

#define S_LEN 2048
#define EMB   1024
#define NH    16
#define HD    64
#define BATCH 2
#define MROWS (BATCH * S_LEN)   // 4096

typedef __attribute__((ext_vector_type(8))) short short8;    // 8 bf16 = 4 VGPR
typedef __attribute__((ext_vector_type(4))) float float4v;   // 4 fp32
typedef __attribute__((ext_vector_type(16))) float f32x16;   // 16 fp32 (32x32 acc)
typedef __attribute__((ext_vector_type(2))) unsigned int uint2v;

#define MFMA16(a, b, c) __builtin_amdgcn_mfma_f32_16x16x32_bf16((a), (b), (c), 0, 0, 0)
#define MFMA32(a, b, c) __builtin_amdgcn_mfma_f32_32x32x16_bf16((a), (b), (c), 0, 0, 0)

typedef unsigned short u16;
typedef unsigned int   u32;

__device__ __forceinline__ u16 f2bf(float f) {
    union { float f; u32 u; } v; v.f = f;
    u32 u = v.u;
    return (u16)((u + 0x7fffu + ((u >> 16) & 1u)) >> 16);  // RNE
}

// packed fp32x2 -> bf16x2 (HW RNE on gfx950; fallback manual)
#if __has_builtin(__builtin_amdgcn_cvt_pk_bf16_f32)
typedef __attribute__((ext_vector_type(2))) __bf16 bfx2;
__device__ __forceinline__ u32 pkbf(float a, float b) {
    union { bfx2 v; u32 u; } c;
    c.v = __builtin_amdgcn_cvt_pk_bf16_f32(a, b);
    return c.u;
}
#else
__device__ __forceinline__ u32 pkbf(float a, float b) {
    return (u32)f2bf(a) | ((u32)f2bf(b) << 16);
}
#endif

#if __has_builtin(__builtin_amdgcn_exp2f)
#define EXP2(x) __builtin_amdgcn_exp2f(x)
#else
#define EXP2(x) exp2f(x)
#endif

// half-wave (lane ^ 32) pair exchange:
//   X = r0: lanes<32 keep a, lanes>=32 get b[lane-32]
//   Y = r1: lanes<32 get a[lane+32], lanes>=32 keep b
#if __has_builtin(__builtin_amdgcn_permlane32_swap)
__device__ __forceinline__ void half_swap(u32 a, u32 b, u32& x, u32& y) {
    uint2v r = __builtin_amdgcn_permlane32_swap(a, b, false, false);
    x = r[0]; y = r[1];
}
#else
__device__ __forceinline__ void half_swap(u32 a, u32 b, u32& x, u32& y) {
    int addr = ((threadIdx.x ^ 32) & 63) << 2;
    u32 asw = (u32)__builtin_amdgcn_ds_bpermute(addr, (int)a);
    u32 bsw = (u32)__builtin_amdgcn_ds_bpermute(addr, (int)b);
    bool hi = (threadIdx.x & 32) != 0;
    x = hi ? bsw : a;
    y = hi ? b : asw;
}
#endif

// async 16B global->LDS (lds dest = wave-uniform base + lane*16)
typedef __attribute__((address_space(3))) unsigned char lds_u8;
typedef __attribute__((address_space(1))) const unsigned char glb_u8;
__device__ __forceinline__ void async_copy16(const void* g, void* l) {
    __builtin_amdgcn_global_load_lds((glb_u8*)g, (lds_u8*)l, 16, 0, 0);
}

// ---------------------------------------------------------------------------
// K0: fused prologue. z=0..3: convert+transpose weight z (Wq pre-scaled by
// 0.125*log2e so QK scores exit the MFMA in exp2 domain). z=4..7: x -> bf16.
// ---------------------------------------------------------------------------
__global__ __launch_bounds__(256) void prep_kernel(
    const float* __restrict__ x,
    const float* __restrict__ W0, const float* __restrict__ W1,
    const float* __restrict__ W2, const float* __restrict__ W3,
    u16* __restrict__ xb, u16* __restrict__ Wt) {
    const int z = blockIdx.z;
    const int tid = threadIdx.x;
    if (z >= 4) {
        int i = ((((z - 4) * 1024) + blockIdx.y * 32 + blockIdx.x) * 256 + tid) * 4;
        float4 f = *(const float4*)(x + i);
        uint2 o; o.x = pkbf(f.x, f.y); o.y = pkbf(f.z, f.w);
        *(uint2*)(xb + i) = o;
        return;
    }
    const float* W = (z == 0) ? W0 : (z == 1) ? W1 : (z == 2) ? W2 : W3;
    u16* dst = Wt + (size_t)z * EMB * EMB;
    const float sc = (z == 0) ? 0.18033688011112042f : 1.0f;
    __shared__ float tile[32][33];
    int c0 = blockIdx.x * 32, r0 = blockIdx.y * 32;
    int tx = tid & 31, ty = tid >> 5;
#pragma unroll
    for (int i = 0; i < 4; ++i)
        tile[ty + 8 * i][tx] = W[(size_t)(r0 + ty + 8 * i) * EMB + c0 + tx];
    __syncthreads();
#pragma unroll
    for (int i = 0; i < 4; ++i)
        dst[(size_t)(c0 + ty + 8 * i) * EMB + r0 + tx] = f2bf(tile[tx][ty + 8 * i] * sc);
}

// ---------------------------------------------------------------------------
// GEMM core (128x128): BK=32, depth-1 LDS double-buffer, xor swizzle
// s(row)=(row>>1)&3 (2-way on banks = free). Prefetch before MFMAs.
// ---------------------------------------------------------------------------
#define GEMM_STEP(B, KN)                                                                       \
    {                                                                                           \
        short8 a[4], b[4];                                                                      \
        _Pragma("unroll")                                                                       \
        for (int i = 0; i < 4; ++i) a[i] = *(const short8*)&As[B][wm * 64 + i * 16 + l15][ca];  \
        _Pragma("unroll")                                                                       \
        for (int j = 0; j < 4; ++j) b[j] = *(const short8*)&Bs[B][wn * 64 + j * 16 + l15][ca];  \
        if ((KN) < EMB) {                                                                       \
            for (int wl = wid; wl < 8; wl += 4) {                                               \
                async_copy16(&Ag[(size_t)(m0 + wl * 16 + rr) * EMB + (KN) + cc], &As[B ^ 1][wl * 16][0]); \
                async_copy16(&Bg[(size_t)(n0 + wl * 16 + rr) * EMB + (KN) + cc], &Bs[B ^ 1][wl * 16][0]); \
            }                                                                                   \
        }                                                                                       \
        _Pragma("unroll")                                                                       \
        for (int i = 0; i < 4; ++i)                                                             \
            _Pragma("unroll")                                                                   \
            for (int j = 0; j < 4; ++j)                                                         \
                acc[i][j] = MFMA16(a[i], b[j], acc[i][j]);                                      \
        __syncthreads();                                                                        \
    }

#define GEMM_CORE(A_, B_)                                                                      \
    const int tid = threadIdx.x;                                                                \
    const int lane = tid & 63, wid = tid >> 6;                                                  \
    const int wm = wid >> 1, wn = wid & 1;                                                      \
    const int l15 = lane & 15, lq = lane >> 4;                                                  \
    const int m0 = blockIdx.y * 128, n0 = blockIdx.x * 128;                                     \
    const u16* Ag = (A_);                                                                       \
    const u16* Bg = (B_);                                                                       \
    __shared__ u16 As[2][128][32];                                                              \
    __shared__ u16 Bs[2][128][32];                                                              \
    float4v acc[4][4] = {};                                                                     \
    const int rr = lane >> 2;                                                                   \
    const int cc = ((lane & 3) ^ ((rr >> 1) & 3)) * 8;                                          \
    const int ca = (lq ^ ((l15 >> 1) & 3)) * 8;                                                 \
    for (int wl = wid; wl < 8; wl += 4) {                                                       \
        async_copy16(&Ag[(size_t)(m0 + wl * 16 + rr) * EMB + cc], &As[0][wl * 16][0]);          \
        async_copy16(&Bg[(size_t)(n0 + wl * 16 + rr) * EMB + cc], &Bs[0][wl * 16][0]);          \
    }                                                                                           \
    __syncthreads();                                                                            \
    for (int k0 = 0; k0 < EMB; k0 += 64) {                                                      \
        GEMM_STEP(0, k0 + 32)                                                                   \
        GEMM_STEP(1, k0 + 64)                                                                   \
    }

// K2: fused 3-projection GEMM: z=0 Q[B,H,S,D], z=1 K[B,H,S,D], z=2 V^T[B,H,D,S]
__global__ __launch_bounds__(256) void gemm_proj_kernel(
    const u16* __restrict__ A, const u16* __restrict__ WtAll,
    u16* __restrict__ Qb, u16* __restrict__ Kb, u16* __restrict__ Vtb) {
    const int z = blockIdx.z;
    const u16* Wt = WtAll + (size_t)z * EMB * EMB;
    GEMM_CORE(A, Wt)
#pragma unroll
    for (int i = 0; i < 4; ++i)
#pragma unroll
        for (int j = 0; j < 4; ++j) {
            int mb = m0 + wm * 64 + i * 16 + lq * 4;      // 4 consecutive m
            int n  = n0 + wn * 64 + j * 16 + l15;
            int b_ = mb >> 11, s = mb & 2047;
            int h = n >> 6, d = n & 63;
            if (z == 2) {
                uint2 pv;
                pv.x = pkbf(acc[i][j][0], acc[i][j][1]);
                pv.y = pkbf(acc[i][j][2], acc[i][j][3]);
                *(uint2*)&Vtb[(((size_t)(b_ * NH + h) * HD + d) * S_LEN) + s] = pv;
            } else {
                u16* dst = (z == 1) ? Kb : Qb;
#pragma unroll
                for (int r = 0; r < 4; ++r)
                    dst[(((size_t)(b_ * NH + h) * S_LEN + s + r) * HD) + d] = f2bf(acc[i][j][r]);
            }
        }
}

// ---------------------------------------------------------------------------
// K4: output GEMM -> fp32. 128m x 64n tiles: grid (16,32) = 512 blocks.
// ---------------------------------------------------------------------------
__global__ __launch_bounds__(256) void gemm_out_kernel(
    const u16* __restrict__ A, const u16* __restrict__ Wt, float* __restrict__ out) {
    const int tid = threadIdx.x;
    const int lane = tid & 63, wid = tid >> 6;
    const int wm = wid >> 1, wn = wid & 1;
    const int l15 = lane & 15, lq = lane >> 4;
    const int m0 = blockIdx.y * 128, n0 = blockIdx.x * 64;
    __shared__ u16 As[2][128][32];
    __shared__ u16 Bs[2][64][32];
    float4v acc[4][2] = {};
    const int rr = lane >> 2;
    const int cc = ((lane & 3) ^ ((rr >> 1) & 3)) * 8;
    const int ca = (lq ^ ((l15 >> 1) & 3)) * 8;

#define GO_STAGE(B, KN)                                                                        \
    {                                                                                           \
        for (int wl = wid; wl < 8; wl += 4)                                                     \
            async_copy16(&A[(size_t)(m0 + wl * 16 + rr) * EMB + (KN) + cc], &As[B][wl * 16][0]);\
        async_copy16(&Wt[(size_t)(n0 + wid * 16 + rr) * EMB + (KN) + cc], &Bs[B][wid * 16][0]); \
    }
#define GO_STEP(B, KN)                                                                         \
    {                                                                                           \
        short8 a[4], b[2];                                                                      \
        _Pragma("unroll")                                                                       \
        for (int i = 0; i < 4; ++i) a[i] = *(const short8*)&As[B][wm * 64 + i * 16 + l15][ca];  \
        _Pragma("unroll")                                                                       \
        for (int j = 0; j < 2; ++j) b[j] = *(const short8*)&Bs[B][wn * 32 + j * 16 + l15][ca];  \
        if ((KN) < EMB) GO_STAGE(B ^ 1, KN)                                                     \
        _Pragma("unroll")                                                                       \
        for (int i = 0; i < 4; ++i)                                                             \
            _Pragma("unroll")                                                                   \
            for (int j = 0; j < 2; ++j)                                                         \
                acc[i][j] = MFMA16(a[i], b[j], acc[i][j]);                                      \
        __syncthreads();                                                                        \
    }

    GO_STAGE(0, 0)
    __syncthreads();
    for (int k0 = 0; k0 < EMB; k0 += 64) {
        GO_STEP(0, k0 + 32)
        GO_STEP(1, k0 + 64)
    }
#pragma unroll
    for (int i = 0; i < 4; ++i)
#pragma unroll
        for (int j = 0; j < 2; ++j)
#pragma unroll
            for (int r = 0; r < 4; ++r) {
                int m = m0 + wm * 64 + i * 16 + lq * 4 + r;
                int n = n0 + wn * 32 + j * 16 + l15;
                out[(size_t)m * EMB + n] = acc[i][j][r];
            }
}

// ---------------------------------------------------------------------------
// K3: flash attention (causal), 32x32x16 MFMA rebuild (m214 structure).
// S^T = K*Q^T per wave over 32 q-cols; lane holds P half-column for
// q = lane&31 (kv split across lane halves) -> PV A-operand assembled fully
// in-register via cvt_pk_bf16 pairs + permlane32_swap (NO P LDS round-trip,
// NO mid-tile lgkmcnt drain). Per 64kv-tile per wave: 8 kf + 8 vf b128 LDS
// reads, 8 QK + 8 PV MFMA(32x32x16) -> LDS bytes/FLOP halved vs 16x16 and
// Ps eliminated. ls = fp32 in-register tree sum + one half-swap (more
// accurate than old bf16 MFMA-ones row-sum).
// 2-wave blocks (wave = 32 q-rows), singleton q-tile, LPT (heavy qt first).
// LDS = Ks[2]+Vs[2] = 32768 B exactly -> 5 blocks/CU; grid 1024.
// ---------------------------------------------------------------------------
#define ATTN_STAGE(B, T)                                                                       \
    {                                                                                           \
        int kv0s = (T) * 64;                                                                    \
        for (int wl = wid; wl < 8; wl += 2) {                                                   \
            async_copy16(&Kb[(size_t)(kv0s + wl * 8 + rr8) * HD + cc8], &Ks[B][wl * 8][0]);     \
            async_copy16(&Vb[(size_t)(wl * 8 + rr8) * S_LEN + kv0s + cc8], &Vs[B][wl * 8][0]);  \
        }                                                                                       \
    }

__global__ __launch_bounds__(128, 3) void attn_kernel(
    const u16* __restrict__ Q, const u16* __restrict__ K,
    const u16* __restrict__ Vt, u16* __restrict__ ctx) {
    const int tid = threadIdx.x;
    const int lane = tid & 63, wid = tid >> 6;   // 2 waves/block
    const int l31 = lane & 31, hi = lane >> 5;
    const int bh = blockIdx.x;                   // x fastest: same-bh blocks same XCD
    const int b = bh >> 4, h = bh & 15;
    const int qt = 31 - (int)blockIdx.y;         // heavy-first (LPT)
    const int q0 = qt * 64;
    const int qw = q0 + wid * 32;                // this wave's 32 q-rows

    const u16* Qb = Q + (size_t)bh * S_LEN * HD;
    const u16* Kb = K + (size_t)bh * S_LEN * HD;
    const u16* Vb = Vt + (size_t)bh * HD * S_LEN;

    __shared__ u16 Ks[2][64][64];   // [kv][d], xor-swizzled 16B chunks (16 KB)
    __shared__ u16 Vs[2][64][64];   // [d][kv], xor-swizzled 16B chunks (16 KB)
    // total LDS = 32768 B exactly -> 5 blocks/CU

    const int rr8 = lane >> 3;
    const int cc8 = ((lane & 7) ^ rr8) * 8;      // staging source swizzle s(row)=row&7
    const int sw7 = l31 & 7;                     // read-side swizzle key (row&7)

    // Q B-frags (32x32x16 B-operand: n = l31 = q row, k(d) = ks*16 + hi*8 + j)
    short8 qf[4];
#pragma unroll
    for (int ks = 0; ks < 4; ++ks)
        qf[ks] = *(const short8*)&Qb[(size_t)(qw + l31) * HD + ks * 16 + hi * 8];

    f32x16 acc0 = {}, acc1 = {};   // O[32q][d 0-31], O[32q][d 32-63]
    float lsum = 0.f;              // this half-lane's partial row-sum (q = l31)

    const int ntiles = qt + 1;
    ATTN_STAGE(0, 0)
    __syncthreads();

    for (int t = 0; t < ntiles; ++t) {
        const u16 (*KsS)[64] = Ks[t & 1];
        const u16 (*VsS)[64] = Vs[t & 1];
        if (t + 1 < ntiles) ATTN_STAGE((t + 1) & 1, t + 1)

        short8 pa0, pa1, pa2, pa3;   // PV A-frags for kv ksteps 0..3
#pragma unroll
        for (int kvb = 0; kvb < 2; ++kvb) {
            // QK: S^T[kv 32-block][q 32] ; A = K rows, B = Q
            f32x16 sc = {};
            __builtin_amdgcn_s_setprio(1);
#pragma unroll
            for (int ks = 0; ks < 4; ++ks) {
                int row = kvb * 32 + l31;
                short8 kfr = *(const short8*)&KsS[row][((ks * 2 + hi) ^ sw7) * 8];
                sc = MFMA32(kfr, qf[ks], sc);
            }
            __builtin_amdgcn_s_setprio(0);
            // causal mask: only the diagonal tile. kv = t*64+kvb*32+crow(r,hi)
            if (t == qt) {
                const int qi = qw + l31;
                const int kvb0 = t * 64 + kvb * 32 + 4 * hi;
#pragma unroll
                for (int r = 0; r < 16; ++r)
                    if (kvb0 + (r & 3) + 8 * (r >> 2) > qi) sc[r] = -__builtin_inff();
            }
            float e0 = EXP2(sc[0]),  e1 = EXP2(sc[1]),  e2 = EXP2(sc[2]),  e3 = EXP2(sc[3]);
            float e4 = EXP2(sc[4]),  e5 = EXP2(sc[5]),  e6 = EXP2(sc[6]),  e7 = EXP2(sc[7]);
            float e8 = EXP2(sc[8]),  e9 = EXP2(sc[9]),  eA = EXP2(sc[10]), eB = EXP2(sc[11]);
            float eC = EXP2(sc[12]), eD = EXP2(sc[13]), eE = EXP2(sc[14]), eF = EXP2(sc[15]);
            lsum += (((e0 + e1) + (e2 + e3)) + ((e4 + e5) + (e6 + e7)))
                  + (((e8 + e9) + (eA + eB)) + ((eC + eD) + (eE + eF)));
            // bf16-pack pairs + half-swap -> A-frag words.
            // frag s (kv 16s..16s+15), word w holds kv (16s + hi*8 + 2w, +1).
            u32 a0 = pkbf(e0, e1), a1 = pkbf(e2, e3);
            u32 a2 = pkbf(e4, e5), a3 = pkbf(e6, e7);
            u32 a4 = pkbf(e8, e9), a5 = pkbf(eA, eB);
            u32 a6 = pkbf(eC, eD), a7 = pkbf(eE, eF);
            u32 w0, w2, w1, w3, x0, x2, x1, x3;
            half_swap(a0, a2, w0, w2);   // s=0: W0 (kv+0,1), W2 (kv+4,5)
            half_swap(a1, a3, w1, w3);   // s=0: W1 (kv+2,3), W3 (kv+6,7)
            half_swap(a4, a6, x0, x2);   // s=1
            half_swap(a5, a7, x1, x3);
            union { u32 u[4]; short8 s8; } f0, f1;
            f0.u[0] = w0; f0.u[1] = w1; f0.u[2] = w2; f0.u[3] = w3;
            f1.u[0] = x0; f1.u[1] = x1; f1.u[2] = x2; f1.u[3] = x3;
            if (kvb == 0) { pa0 = f0.s8; pa1 = f1.s8; }
            else         { pa2 = f0.s8; pa3 = f1.s8; }
        }
        // PV: O[32q][64d] += P[32q, kv16] * V[kv16, d32] over 4 ksteps
        __builtin_amdgcn_s_setprio(1);
#pragma unroll
        for (int ks = 0; ks < 4; ++ks) {
            short8 pf = (ks == 0) ? pa0 : (ks == 1) ? pa1 : (ks == 2) ? pa2 : pa3;
            short8 vf0 = *(const short8*)&VsS[l31][((ks * 2 + hi) ^ sw7) * 8];
            acc0 = MFMA32(pf, vf0, acc0);
            short8 vf1 = *(const short8*)&VsS[32 + l31][((ks * 2 + hi) ^ sw7) * 8];
            acc1 = MFMA32(pf, vf1, acc1);
        }
        __builtin_amdgcn_s_setprio(0);
        __syncthreads();
    }

    // ls: combine half-lanes (q = l31 same for lane^32), broadcast via the
    // stale Ks slot (slot ntiles&1 holds tile ntiles-2: consumed 2 barriers ago)
    union { float f; u32 u; } lu; lu.f = lsum;
    u32 ra, rb;
    half_swap(lu.u, lu.u, ra, rb);
    union { u32 u; float f; } ua, ub; ua.u = ra; ub.u = rb;
    float tot = ua.f + ub.f;   // own + partner (both orders covered)
    float* lsS = (float*)&Ks[ntiles & 1][0][0] + wid * 32;
    lsS[l31] = tot;            // lanes l and l+32 write identical value
#pragma unroll
    for (int r = 0; r < 16; ++r) {
        int q = (r & 3) + 8 * (r >> 2) + 4 * hi;   // C-row mapping
        float lr = 1.f / lsS[q];
        size_t base = ((size_t)b * S_LEN + (qw + q)) * EMB + h * HD;
        ctx[base + l31]      = f2bf(acc0[r] * lr);
        ctx[base + 32 + l31] = f2bf(acc1[r] * lr);
    }
}

// ---------------------------------------------------------------------------
extern "C" void kernel_launch(void* const* d_in, const int* in_sizes, int n_in,
                              void* d_out, int out_size, void* d_ws, size_t ws_size,
                              hipStream_t stream) {
    const float* x  = (const float*)d_in[0];
    const float* wq = (const float*)d_in[1];
    const float* wk = (const float*)d_in[2];
    const float* wv = (const float*)d_in[3];
    const float* wo = (const float*)d_in[4];
    float* out = (float*)d_out;

    u16* ws  = (u16*)d_ws;
    u16* xb  = ws;                             // 4M : x bf16
    u16* Wt  = xb  + (size_t)4 * 1024 * 1024;  // 4M : 4 transposed weights
    u16* Qb  = Wt  + (size_t)4 * 1024 * 1024;  // 4M : Q [B,H,S,D] (pre-scaled)
    u16* Kb  = Qb  + (size_t)4 * 1024 * 1024;  // 4M : K [B,H,S,D]
    u16* Vtb = Kb  + (size_t)4 * 1024 * 1024;  // 4M : V^T [B,H,D,S]
    u16* ctx = Vtb + (size_t)4 * 1024 * 1024;  // 4M : ctx [B,S,E]

    prep_kernel<<<dim3(32, 32, 8), dim3(256), 0, stream>>>(x, wq, wk, wv, wo, xb, Wt);
    gemm_proj_kernel<<<dim3(8, 32, 3), dim3(256), 0, stream>>>(xb, Wt, Qb, Kb, Vtb);
    attn_kernel<<<dim3(32, 32), dim3(128), 0, stream>>>(Qb, Kb, Vtb, ctx);
    gemm_out_kernel<<<dim3(16, 32), dim3(256), 0, stream>>>(ctx, Wt + (size_t)3 * 1024 * 1024, out);
}